// Round 4
// baseline (3426.969 us; speedup 1.0000x reference)
//
#include <hip/hip_runtime.h>
#include <math.h>

#define S_LEN 256
#define B_SZ 8
#define V_SZ 32000
#define E_SZ 300
#define H_SZ 512
#define ER_SZ 64
#define XD 364        // ER + E
#define G4H 2048      // 4*H
#define NCHUNK 500    // 32000 / 64
#define NCAND 64

// ---------------- workspace layout (float units) ----------------
#define F_XPRE 0                          // [2048][2048] f32 = fl(x@W_ih.T + b_ih)
#define F_HS32 (F_XPRE + 2048*2048)       // [256][8][512] f32 h history
#define F_H32  (F_HS32 + 2048*512)        // [2][8][512] f32 h double-buffer
#define F_C32  (F_H32 + 2*4096)           // [8][512] f32 c state
#define F_PV1  (F_C32 + 4096)             // [2048][500] f32 chunk top-1 value
#define F_PV2  (F_PV1 + 2048*500)
#define F_I1   (F_PV2 + 2048*500)         // int chunk top-1 index
#define F_I2   (F_I1 + 2048*500)
// end = 9,351,168 four-byte units = 37.4 MB

// ---------------------------------------------------------------- init
__global__ __launch_bounds__(256) void k_init(const float* __restrict__ hiddens,
                                              float* __restrict__ wsf) {
    int gid = blockIdx.x * 256 + threadIdx.x;
    if (gid < B_SZ * H_SZ) {
        float v = hiddens[gid];
        wsf[F_H32 + gid] = v;   // parity-0 h buffer
        wsf[F_C32 + gid] = v;   // c state
    }
}

// ---------------------------------------------------------------- phase A: X_pre
// np-emulating: per output element, sequential f32 FMA over k=0..363, then +b_ih.
// grid: 1024 blocks (64 s-chunks x 16 u-chunks), 256 threads
__global__ __launch_bounds__(256) void k_xpre(const int* __restrict__ tokens,
                                              const int* __restrict__ relations,
                                              const float* __restrict__ embed,
                                              const float* __restrict__ rel_emb,
                                              const float* __restrict__ W_ih,
                                              const float* __restrict__ b_ih,
                                              float* __restrict__ wsf) {
    __shared__ float xs[32][68];
    __shared__ float wsh[128][68];
    const int tid = threadIdx.x;
    const int sc = blockIdx.x >> 4;
    const int uc = blockIdx.x & 15;
    const int u0 = uc * 128;
    const int row0 = sc * 32;
    const int mg = tid >> 5;   // 8 groups, rows mg + 8*i
    const int ng = tid & 31;   // 32 groups, cols ng + 32*j
    float acc[4][4];
#pragma unroll
    for (int i = 0; i < 4; ++i)
#pragma unroll
        for (int j = 0; j < 4; ++j) acc[i][j] = 0.0f;

    for (int kt = 0; kt < 6; ++kt) {
#pragma unroll
        for (int i = 0; i < 2; ++i) {
            int f = tid + 256 * i;           // 512 float4s
            int r = f >> 4, kk4 = f & 15;
            int rowg = row0 + r;
            int s = rowg >> 3, b = rowg & 7;
            float4 v = make_float4(0.f, 0.f, 0.f, 0.f);
            if (kt == 0) {
                int rid = relations[s * B_SZ + b];
                v = *(const float4*)(rel_emb + (size_t)rid * ER_SZ + kk4 * 4);
            } else {
                int col = (kt - 1) * 64 + kk4 * 4;
                if (col < E_SZ) {
                    int tok = (s == 0) ? 0 : tokens[(s - 1) * B_SZ + b];
                    v = *(const float4*)(embed + (size_t)tok * E_SZ + col);
                }
            }
            *(float4*)(&xs[r][kk4 * 4]) = v;
        }
#pragma unroll
        for (int i = 0; i < 8; ++i) {
            int f = tid + 256 * i;           // 2048 float4s
            int u = f >> 4, kk4 = f & 15;
            int k = kt * 64 + kk4 * 4;
            float4 v = make_float4(0.f, 0.f, 0.f, 0.f);
            if (k < XD) v = *(const float4*)(W_ih + (size_t)(u0 + u) * XD + k);
            *(float4*)(&wsh[u][kk4 * 4]) = v;
        }
        __syncthreads();
        // k strictly ascending within and across tiles -> sequential f32 FMA chain
#pragma unroll
        for (int kk4 = 0; kk4 < 16; ++kk4) {
            float4 bf[4];
#pragma unroll
            for (int j = 0; j < 4; ++j) bf[j] = *(const float4*)(&wsh[ng + 32 * j][kk4 * 4]);
#pragma unroll
            for (int i = 0; i < 4; ++i) {
                float4 af = *(const float4*)(&xs[mg + 8 * i][kk4 * 4]);
#pragma unroll
                for (int j = 0; j < 4; ++j) {
                    acc[i][j] = fmaf(af.x, bf[j].x, acc[i][j]);
                    acc[i][j] = fmaf(af.y, bf[j].y, acc[i][j]);
                    acc[i][j] = fmaf(af.z, bf[j].z, acc[i][j]);
                    acc[i][j] = fmaf(af.w, bf[j].w, acc[i][j]);
                }
            }
        }
        __syncthreads();
    }
#pragma unroll
    for (int j = 0; j < 4; ++j) {
        int gu = u0 + ng + 32 * j;
        float bi = b_ih[gu];
#pragma unroll
        for (int i = 0; i < 4; ++i) {
            int rowg = row0 + mg + 8 * i;
            wsf[F_XPRE + (size_t)rowg * G4H + gu] = __fadd_rn(acc[i][j], bi);
        }
    }
}

// ---------------------------------------------------------------- phase B: ONE LSTM step, np-f32-faithful
// grid: 64 blocks x 256 threads. thread = (g 0..3, u_local 0..7, b 0..7); unit = bid*8+ul.
// gates = fl(fl(xpre + hdot) + b_hh); hdot = sequential f32 FMA over k=0..511.
__global__ __launch_bounds__(256) void k_step(const float* __restrict__ W_hh,
                                              const float* __restrict__ b_hh,
                                              float* __restrict__ wsf, int t) {
    __shared__ float hsh[8 * 520];
    __shared__ float gsh[4][8][8];   // [gate][u_local][b]
    const int tid = threadIdx.x;
    const int bid = blockIdx.x;
    const float* hsrc = wsf + F_H32 + (t & 1) * (B_SZ * H_SZ);
#pragma unroll
    for (int n = 0; n < 16; ++n) {
        int idx = n * 256 + tid;
        hsh[(idx >> 9) * 520 + (idx & 511)] = hsrc[idx];
    }
    __syncthreads();
    const int g = tid >> 6;          // 0..3 (i,f,g,o)
    const int ul = (tid >> 3) & 7;   // 0..7
    const int b = tid & 7;
    const int unit = bid * 8 + ul;
    const int grow = g * H_SZ + unit;
    const float* wrow = W_hh + (size_t)grow * H_SZ;
    const float* hrow = hsh + b * 520;
    float acc = 0.0f;
    for (int k = 0; k < H_SZ; ++k) acc = fmaf(wrow[k], hrow[k], acc);   // sequential chain
    float xp = wsf[F_XPRE + (size_t)t * (B_SZ * G4H) + b * G4H + grow];
    float gate = __fadd_rn(__fadd_rn(xp, acc), b_hh[grow]);
    gsh[g][ul][b] = (g == 2) ? (float)tanh((double)gate)
                             : (float)(1.0 / (1.0 + exp(-(double)gate)));
    __syncthreads();
    if (tid < 64) {
        int ul2 = tid >> 3, b2 = tid & 7;
        float si = gsh[0][ul2][b2];
        float sf = gsh[1][ul2][b2];
        float tg = gsh[2][ul2][b2];
        float so = gsh[3][ul2][b2];
        int hidx = b2 * H_SZ + bid * 8 + ul2;
        float cp = wsf[F_C32 + hidx];
        float cn = __fadd_rn(__fmul_rn(sf, cp), __fmul_rn(si, tg));   // np op order, no FMA
        wsf[F_C32 + hidx] = cn;
        float hn = __fmul_rn(so, (float)tanh((double)cn));
        wsf[F_H32 + (size_t)((t + 1) & 1) * (B_SZ * H_SZ) + hidx] = hn;
        wsf[F_HS32 + (size_t)t * (B_SZ * H_SZ) + hidx] = hn;
    }
}

// ---------------------------------------------------------------- top-2 merge helper
__device__ __forceinline__ void merge2(float& v1, int& i1, float& v2, int& i2,
                                       float ov1, int oi1, float ov2, int oi2) {
    if (ov1 > v1 || (ov1 == v1 && oi1 < i1)) {
        float nv2; int ni2;
        if (v1 > ov2 || (v1 == ov2 && i1 < oi2)) { nv2 = v1; ni2 = i1; }
        else { nv2 = ov2; ni2 = oi2; }
        v1 = ov1; i1 = oi1; v2 = nv2; i2 = ni2;
    } else {
        if (ov1 > v2 || (ov1 == v2 && oi1 < i2)) { v2 = ov1; i2 = oi1; }
    }
}

// ---------------------------------------------------------------- phase C1: f32 screening GEMM + chunk top-2
// grid: 8000 blocks (16 row-tiles x 500 v-chunks), 256 threads
__global__ __launch_bounds__(256) void k_logits(const float* __restrict__ W_out,
                                                const float* __restrict__ b_out,
                                                float* __restrict__ wsf) {
    __shared__ float hssh[128][68];
    __shared__ float wsh2[64][68];
    const int tid = threadIdx.x;
    const int mt = blockIdx.x & 15;
    const int vc = blockIdx.x >> 4;
    const int m0 = mt * 128, v0 = vc * 64;
    const int mg = tid >> 4;
    const int ng = tid & 15;
    const float* hs32 = wsf + F_HS32;
    float acc[8][4];
#pragma unroll
    for (int i = 0; i < 8; ++i)
#pragma unroll
        for (int j = 0; j < 4; ++j) acc[i][j] = 0.0f;

    for (int kt = 0; kt < 8; ++kt) {
#pragma unroll
        for (int i = 0; i < 8; ++i) {
            int f = tid + 256 * i;
            int r = f >> 4, kk4 = f & 15;
            *(float4*)(&hssh[r][kk4 * 4]) =
                *(const float4*)(hs32 + (size_t)(m0 + r) * H_SZ + kt * 64 + kk4 * 4);
        }
#pragma unroll
        for (int i = 0; i < 4; ++i) {
            int f = tid + 256 * i;
            int v = f >> 4, kk4 = f & 15;
            *(float4*)(&wsh2[v][kk4 * 4]) =
                *(const float4*)(W_out + (size_t)(v0 + v) * H_SZ + kt * 64 + kk4 * 4);
        }
        __syncthreads();
#pragma unroll
        for (int kk4 = 0; kk4 < 16; ++kk4) {
            float4 bf[4];
#pragma unroll
            for (int j = 0; j < 4; ++j) bf[j] = *(const float4*)(&wsh2[ng + 16 * j][kk4 * 4]);
#pragma unroll
            for (int i = 0; i < 8; ++i) {
                float4 af = *(const float4*)(&hssh[mg + 16 * i][kk4 * 4]);
#pragma unroll
                for (int j = 0; j < 4; ++j) {
                    acc[i][j] = fmaf(af.x, bf[j].x, acc[i][j]);
                    acc[i][j] = fmaf(af.y, bf[j].y, acc[i][j]);
                    acc[i][j] = fmaf(af.z, bf[j].z, acc[i][j]);
                    acc[i][j] = fmaf(af.w, bf[j].w, acc[i][j]);
                }
            }
        }
        __syncthreads();
    }
    float bo[4];
#pragma unroll
    for (int j = 0; j < 4; ++j) bo[j] = b_out[v0 + ng + 16 * j];
#pragma unroll
    for (int i = 0; i < 8; ++i) {
        float v1 = acc[i][0] + bo[0];
        int i1 = v0 + ng;
        float v2 = -1e30f; int i2 = 0x7fffffff;
#pragma unroll
        for (int j = 1; j < 4; ++j) {
            float v = acc[i][j] + bo[j];
            int ix = v0 + ng + 16 * j;
            if (v > v1 || (v == v1 && ix < i1)) { v2 = v1; i2 = i1; v1 = v; i1 = ix; }
            else if (v > v2 || (v == v2 && ix < i2)) { v2 = v; i2 = ix; }
        }
#pragma unroll
        for (int off = 8; off >= 1; off >>= 1) {
            float ov1 = __shfl_down(v1, off, 16);
            int oi1 = __shfl_down(i1, off, 16);
            float ov2 = __shfl_down(v2, off, 16);
            int oi2 = __shfl_down(i2, off, 16);
            merge2(v1, i1, v2, i2, ov1, oi1, ov2, oi2);
        }
        if (ng == 0) {
            int rowg = m0 + mg + 16 * i;
            wsf[F_PV1 + (size_t)rowg * NCHUNK + vc] = v1;
            wsf[F_PV2 + (size_t)rowg * NCHUNK + vc] = v2;
            ((int*)wsf)[F_I1 + (size_t)rowg * NCHUNK + vc] = i1;
            ((int*)wsf)[F_I2 + (size_t)rowg * NCHUNK + vc] = i2;
        }
    }
}

// ---------------------------------------------------------------- phase C2: np-f32 re-eval + softmax-tie argmax + gather
// grid: 512 blocks x 256 threads; block handles 4 rows (1 wave each)
__global__ __launch_bounds__(256) void k_out(const float* __restrict__ transfer,
                                             const float* __restrict__ W_out,
                                             const float* __restrict__ b_out,
                                             const float* __restrict__ wsf,
                                             float* __restrict__ out) {
    __shared__ int cand[4][NCAND];
    __shared__ int cnt[4];
    __shared__ int chosen[4];
    const float* pv1 = wsf + F_PV1;
    const float* pv2 = wsf + F_PV2;
    const int* pi1 = (const int*)wsf + F_I1;
    const int* pi2 = (const int*)wsf + F_I2;
    const float* hs32 = wsf + F_HS32;
    const int tid = threadIdx.x;
    const int wv = tid >> 6, lane = tid & 63;
    const int row = blockIdx.x * 4 + wv;
    if (tid < 4) cnt[tid] = 0;
    __syncthreads();
    // phase 1: f32 row max over chunk tops (screen space)
    float m = -1e30f;
    for (int c = lane; c < NCHUNK; c += 64) m = fmaxf(m, pv1[(size_t)row * NCHUNK + c]);
#pragma unroll
    for (int off = 32; off >= 1; off >>= 1) m = fmaxf(m, __shfl_xor(m, off, 64));
    float thr = m - 1e-3f;
    // phase 2: collect candidates within delta (screen noise << 1e-3)
    for (int c = lane; c < NCHUNK; c += 64) {
        float a = pv1[(size_t)row * NCHUNK + c];
        if (a >= thr) {
            int p = atomicAdd(&cnt[wv], 1);
            if (p < NCAND) cand[wv][p] = pi1[(size_t)row * NCHUNK + c];
        }
        float bq = pv2[(size_t)row * NCHUNK + c];
        if (bq >= thr) {
            int p = atomicAdd(&cnt[wv], 1);
            if (p < NCAND) cand[wv][p] = pi2[(size_t)row * NCHUNK + c];
        }
    }
    __syncthreads();
    int nc = cnt[wv];
    if (nc > NCAND) nc = NCAND;
    // phase 3: np-f32 logit per candidate (sequential FMA chain, lane = candidate)
    bool active = (lane < nc);
    int v = active ? cand[wv][lane] : 0x7fffffff;
    float l32 = -1e30f;
    if (active && v >= 0 && v < V_SZ) {
        const float* wr = W_out + (size_t)v * H_SZ;
        const float* hr = hs32 + (size_t)row * H_SZ;
        float s = 0.0f;
        for (int k = 0; k < H_SZ; ++k) s = fmaf(wr[k], hr[k], s);
        l32 = __fadd_rn(s, b_out[v]);
    }
    // wave max of l32
    float m32 = l32;
#pragma unroll
    for (int off = 32; off >= 1; off >>= 1) m32 = fmaxf(m32, __shfl_xor(m32, off, 64));
    // np softmax emulation: p = expf(l - max); argmax with FIRST-INDEX tie-break
    float p = active ? expf(l32 - m32) : -1.0f;
#pragma unroll
    for (int off = 32; off >= 1; off >>= 1) {
        float op = __shfl_xor(p, off, 64);
        int ov = __shfl_xor(v, off, 64);
        if (op > p || (op == p && ov < v)) { p = op; v = ov; }
    }
    if (lane == 0) {
        if (v < 0 || v >= V_SZ) v = 0;   // safety
        chosen[wv] = v;
    }
    __syncthreads();
    // phase 4: gather transfer rows (4 rows x 75 float4)
    for (int f = tid; f < 300; f += 256) {
        int r = f / 75, e4 = f - r * 75;
        float4 val = *(const float4*)(transfer + (size_t)chosen[r] * E_SZ + e4 * 4);
        *(float4*)(out + (size_t)(blockIdx.x * 4 + r) * E_SZ + e4 * 4) = val;
    }
}

// ---------------------------------------------------------------- launch
extern "C" void kernel_launch(void* const* d_in, const int* in_sizes, int n_in,
                              void* d_out, int out_size, void* d_ws, size_t ws_size,
                              hipStream_t stream) {
    const int* tokens = (const int*)d_in[0];
    const int* relations = (const int*)d_in[1];
    const float* hiddens = (const float*)d_in[2];
    const float* embed = (const float*)d_in[3];
    const float* transfer = (const float*)d_in[4];
    const float* rel_emb = (const float*)d_in[5];
    const float* W_ih = (const float*)d_in[6];
    const float* W_hh = (const float*)d_in[7];
    const float* b_ih = (const float*)d_in[8];
    const float* b_hh = (const float*)d_in[9];
    const float* W_out = (const float*)d_in[10];
    const float* b_out = (const float*)d_in[11];
    float* wsf = (float*)d_ws;
    float* out = (float*)d_out;

    hipLaunchKernelGGL(k_init, dim3(16), dim3(256), 0, stream, hiddens, wsf);
    hipLaunchKernelGGL(k_xpre, dim3(1024), dim3(256), 0, stream,
                       tokens, relations, embed, rel_emb, W_ih, b_ih, wsf);
    for (int t = 0; t < S_LEN; ++t)
        hipLaunchKernelGGL(k_step, dim3(64), dim3(256), 0, stream, W_hh, b_hh, wsf, t);
    hipLaunchKernelGGL(k_logits, dim3(16 * NCHUNK), dim3(256), 0, stream, W_out, b_out, wsf);
    hipLaunchKernelGGL(k_out, dim3(512), dim3(256), 0, stream,
                       transfer, W_out, b_out, wsf, out);
}